// Round 11
// baseline (1157.012 us; speedup 1.0000x reference)
//
#include <hip/hip_runtime.h>

#define R_REL 10
#define HD 64    // hidden dim, fixed by problem
#define BSH 8    // bucket shift: 256 dst per bucket; N<=131072 -> <=512 buckets
#define KPB (256 * R_REL)   // 2560 keys per bucket
#define SORT_CAP 12288      // LDS edge capacity per bucket (mean 8192, +45 sigma)

typedef __attribute__((ext_vector_type(8))) short short8;
typedef __attribute__((ext_vector_type(4))) float floatx4;
typedef __attribute__((ext_vector_type(8))) unsigned short ushort8;

__device__ inline unsigned short f32_to_bf16_rne(float f) {
    unsigned int u = __float_as_uint(f);
    unsigned int r = (u + 0x7FFFu + ((u >> 16) & 1u)) >> 16;
    return (unsigned short)r;
}
__device__ inline float bf16_to_f32(unsigned short h) {
    return __uint_as_float(((unsigned int)h) << 16);
}
__device__ inline float bf16lo(unsigned int u) { return __uint_as_float(u << 16); }
__device__ inline float bf16hi(unsigned int u) { return __uint_as_float(u & 0xFFFF0000u); }

// async global->LDS, 16B per lane; LDS dest = wave-uniform base + lane*16
__device__ __forceinline__ void gload_lds16(const unsigned short* g, unsigned short* l) {
    __builtin_amdgcn_global_load_lds(
        (const __attribute__((address_space(1))) unsigned int*)g,
        (__attribute__((address_space(3))) unsigned int*)l, 16, 0, 0);
}

// Barrier with counted vmcnt (T4): ensures all but the newest `N` VMEM ops
// retired (in-order counter), so staged global_load_lds data has landed while
// up to N epilogue stores stay in flight across the barrier. sched_barrier(0)
// fences stop hipcc from hoisting memory ops across the inline asm (rule #18).
#define BAR_VMCNT(N)                                              \
    do {                                                          \
        asm volatile("s_waitcnt vmcnt(" #N ")" ::: "memory");     \
        __builtin_amdgcn_sched_barrier(0);                        \
        __builtin_amdgcn_s_barrier();                             \
        __builtin_amdgcn_sched_barrier(0);                        \
    } while (0)

// ================= bucketed CSR build =================
__global__ __launch_bounds__(256) void bhist_kernel(const int* __restrict__ dst,
                                                    int* __restrict__ bcnt, int E) {
    __shared__ int l[512];
    int t = threadIdx.x;
    l[t] = 0; l[t + 256] = 0;
    __syncthreads();
    int e0 = blockIdx.x * 4096;
    for (int i = t; i < 4096; i += 256) {
        int e = e0 + i;
        if (e < E) atomicAdd(&l[dst[e] >> BSH], 1);
    }
    __syncthreads();
    if (l[t]) atomicAdd(&bcnt[t], l[t]);
    if (l[t + 256]) atomicAdd(&bcnt[t + 256], l[t + 256]);
}

__global__ void bscan_kernel(const int* __restrict__ bcnt, int* __restrict__ boff,
                             int* __restrict__ gcursor, int NBK, int E) {
    int t = threadIdx.x;   // 512 threads
    int v = (t < NBK) ? bcnt[t] : 0;
    __shared__ int tmp[512];
    tmp[t] = v;
    __syncthreads();
    for (int off = 1; off < 512; off <<= 1) {
        int u = (t >= off) ? tmp[t - off] : 0;
        __syncthreads();
        tmp[t] += u;
        __syncthreads();
    }
    int excl = tmp[t] - v;
    if (t < NBK) { boff[t] = excl; gcursor[t] = excl; }
    if (t == 0) boff[NBK] = E;
}

// LDS-presorted scatter: counting-sort 4096 edges by bucket in LDS, then
// stream out bucket-ordered -> coalesced run bursts (no partial-line RMW).
// staged entry is packed 4B: (lk << 17) | src, lk = (dst&255)*R + et < 2560.
__global__ __launch_bounds__(256) void bscatter_kernel(const int* __restrict__ src,
                                                       const int* __restrict__ dst,
                                                       const int* __restrict__ et,
                                                       int* __restrict__ gcursor,
                                                       unsigned int* __restrict__ staged,
                                                       int E) {
    __shared__ int lcnt[512];
    __shared__ int lstart[512];
    __shared__ int lbase[512];
    __shared__ int tmp[256];
    __shared__ unsigned int lbuf[4096];       // 16 KB
    __shared__ unsigned short lbkt[4096];     // 8 KB
    int t = threadIdx.x;
    int e0 = blockIdx.x * 4096;
    int nthis = min(4096, E - e0);
    lcnt[t] = 0; lcnt[t + 256] = 0;
    __syncthreads();
    for (int i = t; i < nthis; i += 256) atomicAdd(&lcnt[dst[e0 + i] >> BSH], 1);
    __syncthreads();
    // exclusive scan over 512 bins (2 per thread) + global reservation
    int c0 = lcnt[2 * t], c1 = lcnt[2 * t + 1];
    int ps = c0 + c1;
    tmp[t] = ps;
    __syncthreads();
    for (int off = 1; off < 256; off <<= 1) {
        int u = (t >= off) ? tmp[t - off] : 0;
        __syncthreads();
        tmp[t] += u;
        __syncthreads();
    }
    int ex = tmp[t] - ps;
    lstart[2 * t] = ex; lstart[2 * t + 1] = ex + c0;
    lbase[2 * t]     = (c0 > 0) ? atomicAdd(&gcursor[2 * t], c0) : 0;
    lbase[2 * t + 1] = (c1 > 0) ? atomicAdd(&gcursor[2 * t + 1], c1) : 0;
    __syncthreads();
    lcnt[t] = 0; lcnt[t + 256] = 0;
    __syncthreads();
    // scatter into LDS, bucket-sorted
    for (int i = t; i < nthis; i += 256) {
        int dd = dst[e0 + i];
        int bk = dd >> BSH;
        int lk = (dd & ((1 << BSH) - 1)) * R_REL + et[e0 + i];
        unsigned int p = ((unsigned int)lk << 17) | (unsigned int)src[e0 + i];
        int pos = lstart[bk] + atomicAdd(&lcnt[bk], 1);
        lbuf[pos] = p; lbkt[pos] = (unsigned short)bk;
    }
    __syncthreads();
    // coalesced stream-out: consecutive i in a bucket -> consecutive global pos
    for (int i = t; i < nthis; i += 256) {
        int bk = lbkt[i];
        staged[lbase[bk] + i - lstart[bk]] = lbuf[i];
    }
}

// per-bucket LDS counting sort -> coalesced 4B edata {(rel<<20)|src} + dcnt
// + wrow[key] = 1/cnt per (dst,rel). thread t owns local dst t (10 keys).
__global__ __launch_bounds__(256) void sortfill_kernel(const unsigned int* __restrict__ staged,
                                                       const int* __restrict__ boff,
                                                       int* __restrict__ dcnt,
                                                       unsigned int* __restrict__ edata,
                                                       float* __restrict__ wrow,
                                                       int N, int Ntot) {
    __shared__ int hist[KPB];                 // 10 KB: counts -> cursors
    __shared__ int part[256];                 // 1 KB
    __shared__ int lsrc[SORT_CAP];            // 48 KB
    __shared__ unsigned short lkey[SORT_CAP]; // 24 KB
    int t = threadIdx.x, b = blockIdx.x;
    int s0 = boff[b], s1 = boff[b + 1];
#pragma unroll
    for (int j = 0; j < KPB / 256; ++j) hist[t + j * 256] = 0;
    __syncthreads();
    for (int i = s0 + t; i < s1; i += 256)
        atomicAdd(&hist[staged[i] >> 17], 1);
    __syncthreads();
    // per-local-dst totals + per-key weights (to global wrow); exclusive scan
    int base = t * (KPB / 256);
    int c[KPB / 256];
    int s = 0;
#pragma unroll
    for (int j = 0; j < KPB / 256; ++j) {
        c[j] = hist[base + j]; s += c[j];
        wrow[b * KPB + base + j] = 1.0f / fmaxf((float)c[j], 1.0f);
    }
    int dglob = b * 256 + t;
    if (dglob < Ntot) dcnt[dglob] = s;
    part[t] = s;
    __syncthreads();
    for (int off = 1; off < 256; off <<= 1) {
        int u = (t >= off) ? part[t - off] : 0;
        __syncthreads();
        part[t] += u;
        __syncthreads();
    }
    int run = part[t] - s;
#pragma unroll
    for (int j = 0; j < KPB / 256; ++j) { hist[base + j] = run; run += c[j]; }
    __syncthreads();
    // scatter into LDS at sorted position
    for (int i = s0 + t; i < s1; i += 256) {
        unsigned int p = staged[i];
        int lk = p >> 17;
        int pos = atomicAdd(&hist[lk], 1);
        if (pos < SORT_CAP) { lsrc[pos] = (int)(p & 0x1FFFFu); lkey[pos] = (unsigned short)lk; }
        else {  // overflow fallback (never expected; stays correct)
            int rel = lk % R_REL;
            edata[s0 + pos] = ((unsigned int)rel << 20) | (p & 0x1FFFFu);
        }
    }
    __syncthreads();
    // coalesced stream-out (4B per edge)
    int m = min(s1 - s0, SORT_CAP);
    for (int j = t; j < m; j += 256) {
        int lk = lkey[j];
        int rel = lk % R_REL;
        edata[s0 + j] = ((unsigned int)rel << 20) | (unsigned int)lsrc[j];
    }
}

// ---------------- 3-kernel exclusive scan over N ints ----------------
__global__ void scan1_kernel(const int* __restrict__ cnt, int* __restrict__ bsum, int M) {
    int b = blockIdx.x, tid = threadIdx.x;
    int base = b * 1024 + tid * 4;
    int s = 0;
#pragma unroll
    for (int j = 0; j < 4; ++j) { int i = base + j; if (i < M) s += cnt[i]; }
    for (int off = 32; off > 0; off >>= 1) s += __shfl_down(s, off);
    __shared__ int wsum[4];
    int lane = tid & 63, wid = tid >> 6;
    if (lane == 0) wsum[wid] = s;
    __syncthreads();
    if (tid == 0) bsum[b] = wsum[0] + wsum[1] + wsum[2] + wsum[3];
}

__global__ void scan2_kernel(const int* __restrict__ bsum, int* __restrict__ boff, int NB) {
    int tid = threadIdx.x;           // 1024 threads
    int lane = tid & 63, wid = tid >> 6;
    int v = (tid < NB) ? bsum[tid] : 0;
    int x = v;
    for (int off = 1; off < 64; off <<= 1) { int u = __shfl_up(x, off); if (lane >= off) x += u; }
    __shared__ int wsum[16];
    if (lane == 63) wsum[wid] = x;
    __syncthreads();
    int woff = 0;
    for (int w = 0; w < wid; ++w) woff += wsum[w];
    if (tid < NB) boff[tid] = x + woff - v;   // exclusive
}

__global__ void scan3_kernel(const int* __restrict__ cnt, const int* __restrict__ boff,
                             int* __restrict__ rowptr, int M) {
    int b = blockIdx.x, tid = threadIdx.x;
    int base = b * 1024 + tid * 4;
    int c[4]; int s = 0;
#pragma unroll
    for (int j = 0; j < 4; ++j) { int i = base + j; c[j] = (i < M) ? cnt[i] : 0; s += c[j]; }
    int lane = tid & 63, wid = tid >> 6;
    int x = s;
    for (int off = 1; off < 64; off <<= 1) { int u = __shfl_up(x, off); if (lane >= off) x += u; }
    __shared__ int wsum[4];
    if (lane == 63) wsum[wid] = x;
    __syncthreads();
    int woff = 0;
    for (int w = 0; w < wid; ++w) woff += wsum[w];
    int run = boff[b] + x + woff - s;
#pragma unroll
    for (int j = 0; j < 4; ++j) {
        int i = base + j;
        if (i < M) {
            rowptr[i] = run; run += c[j];
            if (i == M - 1) rowptr[M] = run;
        }
    }
}

// ---------------- hi/lo bf16 split of a f32 array ----------------
__global__ void split_kernel(const float* __restrict__ src, unsigned short* __restrict__ hi,
                             unsigned short* __restrict__ lo, int n) {
    int i = blockIdx.x * 256 + threadIdx.x;
    if (i < n) {
        float v = src[i];
        unsigned short h = f32_to_bf16_rne(v);
        hi[i] = h;
        lo[i] = f32_to_bf16_rne(v - bf16_to_f32(h));
    }
}

// W [R][K][HD] + root [K][HD] f32  ->  Wt hi bf16 [(R+1)][HD][K], with the
// k-index XOR-swizzled per row so that LDS (linear copy of this layout) gives
// conflict-free ds_read_b128 fragment reads: short k' = k ^ ((hd&7)<<3).
__global__ void wsplit_kernel(const float* __restrict__ W, const float* __restrict__ root,
                              unsigned short* __restrict__ hi, int K) {
    int idx = blockIdx.x * 256 + threadIdx.x;
    int total = (R_REL + 1) * HD * K;
    if (idx >= total) return;
    int rel = idx / (HD * K);
    int rem = idx - rel * HD * K;
    int n = rem / K, k = rem - n * K;
    float v = (rel < R_REL) ? W[((size_t)rel * K + k) * HD + n] : root[(size_t)k * HD + n];
    int ks = k ^ ((n & 7) << 3);          // bank-spread swizzle within the row
    hi[rel * HD * K + n * K + ks] = f32_to_bf16_rne(v);
}

// ---------------- per-graph node counts (pool fused into agg) ----------------
__global__ __launch_bounds__(256) void gcnt_kernel(const int* __restrict__ batch,
                                                   float* __restrict__ gcnt, int N) {
    __shared__ int h[64];
    int t = threadIdx.x;
    if (t < 64) h[t] = 0;
    __syncthreads();
    int i0 = blockIdx.x * 4096;
    for (int i = t; i < 4096; i += 256) {
        int n = i0 + i;
        if (n < N) atomicAdd(&h[batch[n]], 1);
    }
    __syncthreads();
    if (t < 64 && h[t]) atomicAdd(&gcnt[t], (float)h[t]);
}

// ---------------- MFMA GEMM v9: min-traffic node-partitioned ----------------
// D[hd][node] = mfma(A=Wh_frag, B=X_frag): 512 threads, 128 nodes per block,
// wave w owns nodes n0+w*16+l16 and ALL 64 hd -- every 128B output line is
// completed by 4 back-to-back stores of ONE wave (measured: zero write
// amplification). 2-pass numerics: XhWh + XlWh (W-lo dropped).
// W tile = hi only, double-buffered LDS via global_load_lds (pre-swizzled).
// Counted-vmcnt barrier keeps the 4 epilogue stores in flight (full blocks).
template <int K>
__global__ __launch_bounds__(512, 6)
void gemm_mfma(const unsigned short* __restrict__ Xhi,
               const unsigned short* __restrict__ Xlo,
               const unsigned short* __restrict__ Wthi,
               unsigned short* __restrict__ hout,
               float* __restrict__ fout, int N) {
    constexpr int NS = K / 32;
    constexpr int TILE_SH = HD * K;        // shorts per W-hi tile
    constexpr int SC = K / 64;             // staged 1KB chunks per wave
    __shared__ unsigned short wlds[2 * TILE_SH];   // 32 KB (K=128) / 16 KB
    const int tid = threadIdx.x;
    const int w = tid >> 6, lane = tid & 63;
    const int quad = lane >> 4, l16 = lane & 15;
    const int n0 = blockIdx.x * 128;
    const int node = n0 + w * 16 + l16;
    const bool valid = node < N;
    const bool full = (n0 + 128 <= N);

    // X fragments (hi+lo) -> registers, loaded once (~32 VGPR)
    short8 Xh[NS], Xl[NS];
#pragma unroll
    for (int s = 0; s < NS; ++s) {
        short8 z;
#pragma unroll
        for (int q = 0; q < 8; ++q) z[q] = 0;
        Xh[s] = z; Xl[s] = z;
        if (valid) {
            Xh[s] = *(const short8*)(Xhi + (size_t)node * K + s * 32 + quad * 8);
            Xl[s] = *(const short8*)(Xlo + (size_t)node * K + s * 32 + quad * 8);
        }
    }

    // async-stage W-hi tile for relation rel into buffer b (SC loads/wave)
    auto stage = [&](int rel, int b) {
        const unsigned short* hsrc = Wthi + (size_t)rel * TILE_SH;
        unsigned short* dst0 = wlds + b * TILE_SH;
#pragma unroll
        for (int j = 0; j < SC; ++j) {
            int q = j * 8 + w;   // 1KB chunk id, wave-uniform
            gload_lds16(hsrc + q * 512 + lane * 8, dst0 + q * 512);
        }
    };

    stage(0, 0);
    BAR_VMCNT(0);   // prologue: full drain, tile 0 resident

    const int swzb = (l16 & 7) << 4;
    const size_t NHD = (size_t)N * HD;

#pragma unroll
    for (int c = 0; c <= R_REL; ++c) {   // rel 0..9 = W, rel 10 = root
        const int cur = c & 1;
        if (c < R_REL) stage(c + 1, cur ^ 1);   // SC loads, land by next barrier
        const char* wb = (const char*)(wlds + cur * TILE_SH);
        floatx4 acc[4];
#pragma unroll
        for (int mt = 0; mt < 4; ++mt) { floatx4 z = {0.f, 0.f, 0.f, 0.f}; acc[mt] = z; }
#pragma unroll
        for (int s = 0; s < NS; ++s) {
            const int koffb = ((s * 32 + quad * 8) * 2) ^ swzb;
#pragma unroll
            for (int mt = 0; mt < 4; ++mt) {
                const int rowb = (mt * 16 + l16) * (K * 2);
                short8 Wh = *(const short8*)(wb + rowb + koffb);
                acc[mt] = __builtin_amdgcn_mfma_f32_16x16x32_bf16(Wh, Xh[s], acc[mt], 0, 0, 0);
                acc[mt] = __builtin_amdgcn_mfma_f32_16x16x32_bf16(Wh, Xl[s], acc[mt], 0, 0, 0);
            }
        }
        // epilogue: 4 stores/wave; this wave alone completes each 128B line.
        // D mapping: row (hd) = mt*16 + quad*4 + r, col (node) = l16
        if (c < R_REL) {
            if (valid) {
                unsigned short* hp = hout + (size_t)c * NHD + (size_t)node * HD;
#pragma unroll
                for (int mt = 0; mt < 4; ++mt) {
                    unsigned int d0 = (unsigned int)f32_to_bf16_rne(acc[mt][0]) |
                                      ((unsigned int)f32_to_bf16_rne(acc[mt][1]) << 16);
                    unsigned int d1 = (unsigned int)f32_to_bf16_rne(acc[mt][2]) |
                                      ((unsigned int)f32_to_bf16_rne(acc[mt][3]) << 16);
                    *(uint2*)(hp + mt * 16 + quad * 4) = make_uint2(d0, d1);
                }
            }
        } else {
            if (valid) {
                float* fp = fout + (size_t)node * HD;
#pragma unroll
                for (int mt = 0; mt < 4; ++mt)
                    *(floatx4*)(fp + mt * 16 + quad * 4) = acc[mt];
            }
        }
        if (c < R_REL) {
            if (full) BAR_VMCNT(4); else BAR_VMCNT(0);
        }
        // last iteration: no barrier; kernel-end drain retires final stores
    }
}

// ---------------- aggregation v4: fused epilogues ---------------------------
// wave per dst; 16 lanes x 8B cover one 128B h-row; quarter = lane>>4 picks
// the edge. edata[e] = (rel<<20)|src (4B); weight 1/cnt comes from wrow via
// lane-broadcast. Epilogue computes relu(acc_root + s + bias) and either
// (MODE 0) writes H1 hi/lo split [replaces fin1] or (MODE 1) atomicAdds into
// pooled[batch[d]] [replaces pool]. ne==0 rows still produce output.
template <int MODE>
__global__ __launch_bounds__(256) void agg_kernel(const unsigned short* __restrict__ hc,
                                                  const int* __restrict__ rowptr,
                                                  const unsigned int* __restrict__ edata,
                                                  const float* __restrict__ wrow,
                                                  const float* __restrict__ accb,
                                                  const float* __restrict__ bias,
                                                  const int* __restrict__ batch,
                                                  unsigned short* __restrict__ hi,
                                                  unsigned short* __restrict__ lo,
                                                  float* __restrict__ pooled,
                                                  int N) {
    int gid = blockIdx.x * 256 + threadIdx.x;
    int d = gid >> 6;
    if (d >= N) return;
    int lane = threadIdx.x & 63;
    int quarter = lane >> 4, l16 = lane & 15;
    float w10 = (lane < R_REL) ? wrow[d * R_REL + lane] : 0.f;
    int e0 = rowptr[d], e1 = rowptr[d + 1];
    int ne = e1 - e0;
    float s0 = 0.f, s1 = 0.f, s2 = 0.f, s3 = 0.f;
    for (int rb = 0; rb < ne; rb += 64) {
        int nthis = min(64, ne - rb);
        unsigned int k = (lane < nthis) ? edata[e0 + rb + lane] : 0u;
        int src = (int)(k & 0xFFFFFu);
        int rel = (int)(k >> 20);
        int off = (rel * N + src) << 6;          // * HD
        float wv = __shfl(w10, rel);
        if (lane >= nthis) wv = 0.f;             // pad lanes contribute 0
        for (int j = 0; j < nthis; j += 8) {
            int   oa = __shfl(off, j + quarter);
            float wa = __shfl(wv,  j + quarter);
            int   ob = __shfl(off, j + 4 + quarter);
            float wb = __shfl(wv,  j + 4 + quarter);
            uint2 da = *(const uint2*)(hc + oa + l16 * 4);
            uint2 db = *(const uint2*)(hc + ob + l16 * 4);
            s0 += wa * bf16lo(da.x); s1 += wa * bf16hi(da.x);
            s2 += wa * bf16lo(da.y); s3 += wa * bf16hi(da.y);
            s0 += wb * bf16lo(db.x); s1 += wb * bf16hi(db.x);
            s2 += wb * bf16lo(db.y); s3 += wb * bf16hi(db.y);
        }
    }
    s0 += __shfl_xor(s0, 16); s1 += __shfl_xor(s1, 16);
    s2 += __shfl_xor(s2, 16); s3 += __shfl_xor(s3, 16);
    s0 += __shfl_xor(s0, 32); s1 += __shfl_xor(s1, 32);
    s2 += __shfl_xor(s2, 32); s3 += __shfl_xor(s3, 32);
    if (lane < 16) {
        const float4 a = *(const float4*)(accb + (size_t)d * HD + l16 * 4);
        const float4 b4 = *(const float4*)(bias + l16 * 4);
        float v0 = fmaxf(a.x + s0 + b4.x, 0.f);
        float v1 = fmaxf(a.y + s1 + b4.y, 0.f);
        float v2 = fmaxf(a.z + s2 + b4.z, 0.f);
        float v3 = fmaxf(a.w + s3 + b4.w, 0.f);
        if (MODE == 0) {
            unsigned short h0 = f32_to_bf16_rne(v0), h1 = f32_to_bf16_rne(v1);
            unsigned short h2 = f32_to_bf16_rne(v2), h3 = f32_to_bf16_rne(v3);
            unsigned short l0 = f32_to_bf16_rne(v0 - bf16_to_f32(h0));
            unsigned short l1 = f32_to_bf16_rne(v1 - bf16_to_f32(h1));
            unsigned short l2 = f32_to_bf16_rne(v2 - bf16_to_f32(h2));
            unsigned short l3 = f32_to_bf16_rne(v3 - bf16_to_f32(h3));
            size_t o = (size_t)d * HD + l16 * 4;
            *(uint2*)(hi + o) = make_uint2((unsigned int)h0 | ((unsigned int)h1 << 16),
                                           (unsigned int)h2 | ((unsigned int)h3 << 16));
            *(uint2*)(lo + o) = make_uint2((unsigned int)l0 | ((unsigned int)l1 << 16),
                                           (unsigned int)l2 | ((unsigned int)l3 << 16));
        } else {
            int g = batch[d];
            float* pp = pooled + g * HD + l16 * 4;
            atomicAdd(pp + 0, v0); atomicAdd(pp + 1, v1);
            atomicAdd(pp + 2, v2); atomicAdd(pp + 3, v3);
        }
    }
}

__global__ void cls_kernel(const float* __restrict__ pooled, const float* __restrict__ gcnt,
                           const float* __restrict__ cls_w, const float* __restrict__ cls_b,
                           float* __restrict__ out) {
    int g = threadIdx.x;   // 64 graphs
    float invc = 1.0f / fmaxf(gcnt[g], 1.0f);
    float acc = 0.f;
    for (int j = 0; j < 64; ++j) acc += pooled[g * 64 + j] * cls_w[j];
    out[g] = acc * invc + cls_b[0];
}

extern "C" void kernel_launch(void* const* d_in, const int* in_sizes, int n_in,
                              void* d_out, int out_size, void* d_ws, size_t ws_size,
                              hipStream_t stream) {
    const float* x     = (const float*)d_in[0];
    const int*   eidx  = (const int*)d_in[1];
    const int*   et    = (const int*)d_in[2];
    const int*   batch = (const int*)d_in[3];
    const float* W1    = (const float*)d_in[4];
    const float* root1 = (const float*)d_in[5];
    const float* b1    = (const float*)d_in[6];
    const float* W2    = (const float*)d_in[7];
    const float* root2 = (const float*)d_in[8];
    const float* b2    = (const float*)d_in[9];
    const float* cls_w = (const float*)d_in[10];
    const float* cls_b = (const float*)d_in[11];

    const int N = in_sizes[3];
    const int E = in_sizes[2];
    const int NB = (N + 1023) / 1024;              // scan blocks over N
    const int NBK = (N + (1 << BSH) - 1) >> BSH;   // <=512 buckets
    const int* srcp = eidx;
    const int* dstp = eidx + E;

    char* ws = (char*)d_ws;
    size_t off = 0;
    auto alloc = [&](size_t bytes) -> void* {
        void* p = ws + off;
        off = (off + bytes + 255) & ~(size_t)255;
        return p;
    };
    unsigned short* Xhi  = (unsigned short*)alloc((size_t)N * 128 * 2);   // 25.6 MB
    unsigned short* Xlo  = (unsigned short*)alloc((size_t)N * 128 * 2);   // 25.6 MB
    float*          accb = (float*)alloc((size_t)N * HD * 4);             // 25.6 MB
    unsigned short* Wt1hi = (unsigned short*)alloc((size_t)(R_REL + 1) * HD * 128 * 2);
    unsigned short* Wt2hi = (unsigned short*)alloc((size_t)(R_REL + 1) * HD * HD * 2);
    unsigned int* edata  = (unsigned int*)alloc((size_t)E * 4);           // 12.8 MB
    float* wrow   = (float*)alloc((size_t)NBK * KPB * 4);                 // ~4 MB
    int*   rowptr = (int*)alloc((size_t)(N + 1) * 4);
    int*   dcnt   = (int*)alloc((size_t)N * 4);
    int*   bsum   = (int*)alloc((size_t)NB * 4);
    int*   bofs   = (int*)alloc((size_t)NB * 4);
    int*   bcnt   = (int*)alloc(512 * 4);
    int*   bboff  = (int*)alloc(513 * 4);
    int*   gcur   = (int*)alloc(512 * 4);
    float* pooled = (float*)alloc((size_t)(64 * HD + 64) * 4);
    float* gcnt   = pooled + 64 * HD;
    unsigned short* h_chunk = (unsigned short*)alloc((size_t)R_REL * N * HD * 2);  // 128 MB

    // aliases (stream-ordered, safe):
    // staged (12.8 MB packed) over Xhi: consumed by sortfill before split writes Xhi.
    // H1hi/H1lo over Xhi/Xlo: written by agg<0> AFTER the last gemm read of X.
    unsigned int* staged = (unsigned int*)Xhi;
    unsigned short* H1hi = Xhi;
    unsigned short* H1lo = Xlo;

    hipMemsetAsync(bcnt, 0, 512 * 4, stream);
    hipMemsetAsync(pooled, 0, (size_t)(64 * HD + 64) * 4, stream);

    // ---- per-graph node counts (for cls; pool fused into agg<1>) ----
    gcnt_kernel<<<(N + 4095) / 4096, 256, 0, stream>>>(batch, gcnt, N);

    // ---- bucketed CSR build: edata {(rel<<20)|src} + wrow + dst rowptr ----
    int nchunks = (E + 4095) / 4096;
    bhist_kernel<<<nchunks, 256, 0, stream>>>(dstp, bcnt, E);
    bscan_kernel<<<1, 512, 0, stream>>>(bcnt, bboff, gcur, NBK, E);
    bscatter_kernel<<<nchunks, 256, 0, stream>>>(srcp, dstp, et, gcur, staged, E);
    sortfill_kernel<<<NBK, 256, 0, stream>>>(staged, bboff, dcnt, edata, wrow, N, N);
    scan1_kernel<<<NB, 256, 0, stream>>>(dcnt, bsum, N);
    scan2_kernel<<<1, 1024, 0, stream>>>(bsum, bofs, NB);
    scan3_kernel<<<NB, 256, 0, stream>>>(dcnt, bofs, rowptr, N);

    // ---- precision-split operands (after staged is dead) ----
    int NK = N * 128;
    split_kernel<<<(NK + 255) / 256, 256, 0, stream>>>(x, Xhi, Xlo, NK);
    int tw1 = (R_REL + 1) * HD * 128, tw2 = (R_REL + 1) * HD * HD;
    wsplit_kernel<<<(tw1 + 255) / 256, 256, 0, stream>>>(W1, root1, Wt1hi, 128);
    wsplit_kernel<<<(tw2 + 255) / 256, 256, 0, stream>>>(W2, root2, Wt2hi, HD);

    const int gemmBlocks = (N + 127) / 128;
    const int aggBlocks  = (int)(((size_t)N * 64 + 255) / 256);

    // ---- layer 1 (K=128): rels 0..9 -> h_chunk, root -> accb; agg writes H1 ----
    gemm_mfma<128><<<gemmBlocks, 512, 0, stream>>>(Xhi, Xlo, Wt1hi, h_chunk, accb, N);
    agg_kernel<0><<<aggBlocks, 256, 0, stream>>>(h_chunk, rowptr, edata, wrow, accb, b1,
                                                 batch, H1hi, H1lo, pooled, N);

    // ---- layer 2 (K=64): rels 0..9 -> h_chunk, root -> accb; agg pools ----
    gemm_mfma<64><<<gemmBlocks, 512, 0, stream>>>(H1hi, H1lo, Wt2hi, h_chunk, accb, N);
    agg_kernel<1><<<aggBlocks, 256, 0, stream>>>(h_chunk, rowptr, edata, wrow, accb, b2,
                                                 batch, (unsigned short*)nullptr,
                                                 (unsigned short*)nullptr, pooled, N);

    // ---- classify ----
    cls_kernel<<<1, 64, 0, stream>>>(pooled, gcnt, cls_w, cls_b, (float*)d_out);
}

// Round 12
// 559.375 us; speedup vs baseline: 2.0684x; 2.0684x over previous
//
#include <hip/hip_runtime.h>

#define R_REL 10
#define HD 64    // hidden dim, fixed by problem
#define BSH 8    // bucket shift: 256 dst per bucket; N<=131072 -> <=512 buckets
#define KPB (256 * R_REL)   // 2560 keys per bucket
#define SORT_CAP 12288      // LDS edge capacity per bucket (mean 8192, +45 sigma)

typedef __attribute__((ext_vector_type(8))) short short8;
typedef __attribute__((ext_vector_type(4))) float floatx4;
typedef __attribute__((ext_vector_type(8))) unsigned short ushort8;

__device__ inline unsigned short f32_to_bf16_rne(float f) {
    unsigned int u = __float_as_uint(f);
    unsigned int r = (u + 0x7FFFu + ((u >> 16) & 1u)) >> 16;
    return (unsigned short)r;
}
__device__ inline float bf16_to_f32(unsigned short h) {
    return __uint_as_float(((unsigned int)h) << 16);
}
__device__ inline float bf16lo(unsigned int u) { return __uint_as_float(u << 16); }
__device__ inline float bf16hi(unsigned int u) { return __uint_as_float(u & 0xFFFF0000u); }

// async global->LDS, 16B per lane; LDS dest = wave-uniform base + lane*16
__device__ __forceinline__ void gload_lds16(const unsigned short* g, unsigned short* l) {
    __builtin_amdgcn_global_load_lds(
        (const __attribute__((address_space(1))) unsigned int*)g,
        (__attribute__((address_space(3))) unsigned int*)l, 16, 0, 0);
}

// Barrier with counted vmcnt (T4): ensures all but the newest `N` VMEM ops
// retired (in-order counter), so staged global_load_lds data has landed while
// up to N epilogue stores stay in flight across the barrier. sched_barrier(0)
// fences stop hipcc from hoisting memory ops across the inline asm (rule #18).
#define BAR_VMCNT(N)                                              \
    do {                                                          \
        asm volatile("s_waitcnt vmcnt(" #N ")" ::: "memory");     \
        __builtin_amdgcn_sched_barrier(0);                        \
        __builtin_amdgcn_s_barrier();                             \
        __builtin_amdgcn_sched_barrier(0);                        \
    } while (0)

// ================= bucketed CSR build =================
__global__ __launch_bounds__(256) void bhist_kernel(const int* __restrict__ dst,
                                                    int* __restrict__ bcnt, int E) {
    __shared__ int l[512];
    int t = threadIdx.x;
    l[t] = 0; l[t + 256] = 0;
    __syncthreads();
    int e0 = blockIdx.x * 4096;
    for (int i = t; i < 4096; i += 256) {
        int e = e0 + i;
        if (e < E) atomicAdd(&l[dst[e] >> BSH], 1);
    }
    __syncthreads();
    if (l[t]) atomicAdd(&bcnt[t], l[t]);
    if (l[t + 256]) atomicAdd(&bcnt[t + 256], l[t + 256]);
}

__global__ void bscan_kernel(const int* __restrict__ bcnt, int* __restrict__ boff,
                             int* __restrict__ gcursor, int NBK, int E) {
    int t = threadIdx.x;   // 512 threads
    int v = (t < NBK) ? bcnt[t] : 0;
    __shared__ int tmp[512];
    tmp[t] = v;
    __syncthreads();
    for (int off = 1; off < 512; off <<= 1) {
        int u = (t >= off) ? tmp[t - off] : 0;
        __syncthreads();
        tmp[t] += u;
        __syncthreads();
    }
    int excl = tmp[t] - v;
    if (t < NBK) { boff[t] = excl; gcursor[t] = excl; }
    if (t == 0) boff[NBK] = E;
}

// LDS-presorted scatter: counting-sort 4096 edges by bucket in LDS, then
// stream out bucket-ordered -> coalesced run bursts (no partial-line RMW).
// staged entry is packed 4B: (lk << 17) | src, lk = (dst&255)*R + et < 2560.
__global__ __launch_bounds__(256) void bscatter_kernel(const int* __restrict__ src,
                                                       const int* __restrict__ dst,
                                                       const int* __restrict__ et,
                                                       int* __restrict__ gcursor,
                                                       unsigned int* __restrict__ staged,
                                                       int E) {
    __shared__ int lcnt[512];
    __shared__ int lstart[512];
    __shared__ int lbase[512];
    __shared__ int tmp[256];
    __shared__ unsigned int lbuf[4096];       // 16 KB
    __shared__ unsigned short lbkt[4096];     // 8 KB
    int t = threadIdx.x;
    int e0 = blockIdx.x * 4096;
    int nthis = min(4096, E - e0);
    lcnt[t] = 0; lcnt[t + 256] = 0;
    __syncthreads();
    for (int i = t; i < nthis; i += 256) atomicAdd(&lcnt[dst[e0 + i] >> BSH], 1);
    __syncthreads();
    // exclusive scan over 512 bins (2 per thread) + global reservation
    int c0 = lcnt[2 * t], c1 = lcnt[2 * t + 1];
    int ps = c0 + c1;
    tmp[t] = ps;
    __syncthreads();
    for (int off = 1; off < 256; off <<= 1) {
        int u = (t >= off) ? tmp[t - off] : 0;
        __syncthreads();
        tmp[t] += u;
        __syncthreads();
    }
    int ex = tmp[t] - ps;
    lstart[2 * t] = ex; lstart[2 * t + 1] = ex + c0;
    lbase[2 * t]     = (c0 > 0) ? atomicAdd(&gcursor[2 * t], c0) : 0;
    lbase[2 * t + 1] = (c1 > 0) ? atomicAdd(&gcursor[2 * t + 1], c1) : 0;
    __syncthreads();
    lcnt[t] = 0; lcnt[t + 256] = 0;
    __syncthreads();
    // scatter into LDS, bucket-sorted
    for (int i = t; i < nthis; i += 256) {
        int dd = dst[e0 + i];
        int bk = dd >> BSH;
        int lk = (dd & ((1 << BSH) - 1)) * R_REL + et[e0 + i];
        unsigned int p = ((unsigned int)lk << 17) | (unsigned int)src[e0 + i];
        int pos = lstart[bk] + atomicAdd(&lcnt[bk], 1);
        lbuf[pos] = p; lbkt[pos] = (unsigned short)bk;
    }
    __syncthreads();
    // coalesced stream-out: consecutive i in a bucket -> consecutive global pos
    for (int i = t; i < nthis; i += 256) {
        int bk = lbkt[i];
        staged[lbase[bk] + i - lstart[bk]] = lbuf[i];
    }
}

// per-bucket LDS counting sort -> coalesced 4B edata {(rel<<20)|src} + dcnt
// + wrow[key] = 1/cnt per (dst,rel). thread t owns local dst t (10 keys).
__global__ __launch_bounds__(256) void sortfill_kernel(const unsigned int* __restrict__ staged,
                                                       const int* __restrict__ boff,
                                                       int* __restrict__ dcnt,
                                                       unsigned int* __restrict__ edata,
                                                       float* __restrict__ wrow,
                                                       int N, int Ntot) {
    __shared__ int hist[KPB];                 // 10 KB: counts -> cursors
    __shared__ int part[256];                 // 1 KB
    __shared__ int lsrc[SORT_CAP];            // 48 KB
    __shared__ unsigned short lkey[SORT_CAP]; // 24 KB
    int t = threadIdx.x, b = blockIdx.x;
    int s0 = boff[b], s1 = boff[b + 1];
#pragma unroll
    for (int j = 0; j < KPB / 256; ++j) hist[t + j * 256] = 0;
    __syncthreads();
    for (int i = s0 + t; i < s1; i += 256)
        atomicAdd(&hist[staged[i] >> 17], 1);
    __syncthreads();
    // per-local-dst totals + per-key weights (to global wrow); exclusive scan
    int base = t * (KPB / 256);
    int c[KPB / 256];
    int s = 0;
#pragma unroll
    for (int j = 0; j < KPB / 256; ++j) {
        c[j] = hist[base + j]; s += c[j];
        wrow[b * KPB + base + j] = 1.0f / fmaxf((float)c[j], 1.0f);
    }
    int dglob = b * 256 + t;
    if (dglob < Ntot) dcnt[dglob] = s;
    part[t] = s;
    __syncthreads();
    for (int off = 1; off < 256; off <<= 1) {
        int u = (t >= off) ? part[t - off] : 0;
        __syncthreads();
        part[t] += u;
        __syncthreads();
    }
    int run = part[t] - s;
#pragma unroll
    for (int j = 0; j < KPB / 256; ++j) { hist[base + j] = run; run += c[j]; }
    __syncthreads();
    // scatter into LDS at sorted position
    for (int i = s0 + t; i < s1; i += 256) {
        unsigned int p = staged[i];
        int lk = p >> 17;
        int pos = atomicAdd(&hist[lk], 1);
        if (pos < SORT_CAP) { lsrc[pos] = (int)(p & 0x1FFFFu); lkey[pos] = (unsigned short)lk; }
        else {  // overflow fallback (never expected; stays correct)
            int rel = lk % R_REL;
            edata[s0 + pos] = ((unsigned int)rel << 20) | (p & 0x1FFFFu);
        }
    }
    __syncthreads();
    // coalesced stream-out (4B per edge)
    int m = min(s1 - s0, SORT_CAP);
    for (int j = t; j < m; j += 256) {
        int lk = lkey[j];
        int rel = lk % R_REL;
        edata[s0 + j] = ((unsigned int)rel << 20) | (unsigned int)lsrc[j];
    }
}

// ---------------- 3-kernel exclusive scan over N ints ----------------
__global__ void scan1_kernel(const int* __restrict__ cnt, int* __restrict__ bsum, int M) {
    int b = blockIdx.x, tid = threadIdx.x;
    int base = b * 1024 + tid * 4;
    int s = 0;
#pragma unroll
    for (int j = 0; j < 4; ++j) { int i = base + j; if (i < M) s += cnt[i]; }
    for (int off = 32; off > 0; off >>= 1) s += __shfl_down(s, off);
    __shared__ int wsum[4];
    int lane = tid & 63, wid = tid >> 6;
    if (lane == 0) wsum[wid] = s;
    __syncthreads();
    if (tid == 0) bsum[b] = wsum[0] + wsum[1] + wsum[2] + wsum[3];
}

__global__ void scan2_kernel(const int* __restrict__ bsum, int* __restrict__ boff, int NB) {
    int tid = threadIdx.x;           // 1024 threads
    int lane = tid & 63, wid = tid >> 6;
    int v = (tid < NB) ? bsum[tid] : 0;
    int x = v;
    for (int off = 1; off < 64; off <<= 1) { int u = __shfl_up(x, off); if (lane >= off) x += u; }
    __shared__ int wsum[16];
    if (lane == 63) wsum[wid] = x;
    __syncthreads();
    int woff = 0;
    for (int w = 0; w < wid; ++w) woff += wsum[w];
    if (tid < NB) boff[tid] = x + woff - v;   // exclusive
}

__global__ void scan3_kernel(const int* __restrict__ cnt, const int* __restrict__ boff,
                             int* __restrict__ rowptr, int M) {
    int b = blockIdx.x, tid = threadIdx.x;
    int base = b * 1024 + tid * 4;
    int c[4]; int s = 0;
#pragma unroll
    for (int j = 0; j < 4; ++j) { int i = base + j; c[j] = (i < M) ? cnt[i] : 0; s += c[j]; }
    int lane = tid & 63, wid = tid >> 6;
    int x = s;
    for (int off = 1; off < 64; off <<= 1) { int u = __shfl_up(x, off); if (lane >= off) x += u; }
    __shared__ int wsum[4];
    if (lane == 63) wsum[wid] = x;
    __syncthreads();
    int woff = 0;
    for (int w = 0; w < wid; ++w) woff += wsum[w];
    int run = boff[b] + x + woff - s;
#pragma unroll
    for (int j = 0; j < 4; ++j) {
        int i = base + j;
        if (i < M) {
            rowptr[i] = run; run += c[j];
            if (i == M - 1) rowptr[M] = run;
        }
    }
}

// ---------------- hi/lo bf16 split of a f32 array ----------------
__global__ void split_kernel(const float* __restrict__ src, unsigned short* __restrict__ hi,
                             unsigned short* __restrict__ lo, int n) {
    int i = blockIdx.x * 256 + threadIdx.x;
    if (i < n) {
        float v = src[i];
        unsigned short h = f32_to_bf16_rne(v);
        hi[i] = h;
        lo[i] = f32_to_bf16_rne(v - bf16_to_f32(h));
    }
}

// W [R][K][HD] + root [K][HD] f32  ->  Wt hi bf16 [(R+1)][HD][K], with the
// k-index XOR-swizzled per row so that LDS (linear copy of this layout) gives
// conflict-free ds_read_b128 fragment reads: short k' = k ^ ((hd&7)<<3).
__global__ void wsplit_kernel(const float* __restrict__ W, const float* __restrict__ root,
                              unsigned short* __restrict__ hi, int K) {
    int idx = blockIdx.x * 256 + threadIdx.x;
    int total = (R_REL + 1) * HD * K;
    if (idx >= total) return;
    int rel = idx / (HD * K);
    int rem = idx - rel * HD * K;
    int n = rem / K, k = rem - n * K;
    float v = (rel < R_REL) ? W[((size_t)rel * K + k) * HD + n] : root[(size_t)k * HD + n];
    int ks = k ^ ((n & 7) << 3);          // bank-spread swizzle within the row
    hi[rel * HD * K + n * K + ks] = f32_to_bf16_rne(v);
}

// ---------------- MFMA GEMM v9: min-traffic node-partitioned ----------------
// D[hd][node] = mfma(A=Wh_frag, B=X_frag): 512 threads, 128 nodes per block,
// wave w owns nodes n0+w*16+l16 and ALL 64 hd -- every 128B output line is
// completed by 4 back-to-back stores of ONE wave (measured: zero write
// amplification). 2-pass numerics: XhWh + XlWh (W-lo dropped).
// W tile = hi only, double-buffered LDS via global_load_lds (pre-swizzled).
// Counted-vmcnt barrier keeps the 4 epilogue stores in flight (full blocks).
template <int K>
__global__ __launch_bounds__(512, 6)
void gemm_mfma(const unsigned short* __restrict__ Xhi,
               const unsigned short* __restrict__ Xlo,
               const unsigned short* __restrict__ Wthi,
               unsigned short* __restrict__ hout,
               float* __restrict__ fout, int N) {
    constexpr int NS = K / 32;
    constexpr int TILE_SH = HD * K;        // shorts per W-hi tile
    constexpr int SC = K / 64;             // staged 1KB chunks per wave
    __shared__ unsigned short wlds[2 * TILE_SH];   // 32 KB (K=128) / 16 KB
    const int tid = threadIdx.x;
    const int w = tid >> 6, lane = tid & 63;
    const int quad = lane >> 4, l16 = lane & 15;
    const int n0 = blockIdx.x * 128;
    const int node = n0 + w * 16 + l16;
    const bool valid = node < N;
    const bool full = (n0 + 128 <= N);

    // X fragments (hi+lo) -> registers, loaded once (~32 VGPR)
    short8 Xh[NS], Xl[NS];
#pragma unroll
    for (int s = 0; s < NS; ++s) {
        short8 z;
#pragma unroll
        for (int q = 0; q < 8; ++q) z[q] = 0;
        Xh[s] = z; Xl[s] = z;
        if (valid) {
            Xh[s] = *(const short8*)(Xhi + (size_t)node * K + s * 32 + quad * 8);
            Xl[s] = *(const short8*)(Xlo + (size_t)node * K + s * 32 + quad * 8);
        }
    }

    // async-stage W-hi tile for relation rel into buffer b (SC loads/wave)
    auto stage = [&](int rel, int b) {
        const unsigned short* hsrc = Wthi + (size_t)rel * TILE_SH;
        unsigned short* dst0 = wlds + b * TILE_SH;
#pragma unroll
        for (int j = 0; j < SC; ++j) {
            int q = j * 8 + w;   // 1KB chunk id, wave-uniform
            gload_lds16(hsrc + q * 512 + lane * 8, dst0 + q * 512);
        }
    };

    stage(0, 0);
    BAR_VMCNT(0);   // prologue: full drain, tile 0 resident

    const int swzb = (l16 & 7) << 4;
    const size_t NHD = (size_t)N * HD;

#pragma unroll
    for (int c = 0; c <= R_REL; ++c) {   // rel 0..9 = W, rel 10 = root
        const int cur = c & 1;
        if (c < R_REL) stage(c + 1, cur ^ 1);   // SC loads, land by next barrier
        const char* wb = (const char*)(wlds + cur * TILE_SH);
        floatx4 acc[4];
#pragma unroll
        for (int mt = 0; mt < 4; ++mt) { floatx4 z = {0.f, 0.f, 0.f, 0.f}; acc[mt] = z; }
#pragma unroll
        for (int s = 0; s < NS; ++s) {
            const int koffb = ((s * 32 + quad * 8) * 2) ^ swzb;
#pragma unroll
            for (int mt = 0; mt < 4; ++mt) {
                const int rowb = (mt * 16 + l16) * (K * 2);
                short8 Wh = *(const short8*)(wb + rowb + koffb);
                acc[mt] = __builtin_amdgcn_mfma_f32_16x16x32_bf16(Wh, Xh[s], acc[mt], 0, 0, 0);
                acc[mt] = __builtin_amdgcn_mfma_f32_16x16x32_bf16(Wh, Xl[s], acc[mt], 0, 0, 0);
            }
        }
        // epilogue: 4 stores/wave; this wave alone completes each 128B line.
        // D mapping: row (hd) = mt*16 + quad*4 + r, col (node) = l16
        if (c < R_REL) {
            if (valid) {
                unsigned short* hp = hout + (size_t)c * NHD + (size_t)node * HD;
#pragma unroll
                for (int mt = 0; mt < 4; ++mt) {
                    unsigned int d0 = (unsigned int)f32_to_bf16_rne(acc[mt][0]) |
                                      ((unsigned int)f32_to_bf16_rne(acc[mt][1]) << 16);
                    unsigned int d1 = (unsigned int)f32_to_bf16_rne(acc[mt][2]) |
                                      ((unsigned int)f32_to_bf16_rne(acc[mt][3]) << 16);
                    *(uint2*)(hp + mt * 16 + quad * 4) = make_uint2(d0, d1);
                }
            }
        } else {
            if (valid) {
                float* fp = fout + (size_t)node * HD;
#pragma unroll
                for (int mt = 0; mt < 4; ++mt)
                    *(floatx4*)(fp + mt * 16 + quad * 4) = acc[mt];
            }
        }
        if (c < R_REL) {
            if (full) BAR_VMCNT(4); else BAR_VMCNT(0);
        }
        // last iteration: no barrier; kernel-end drain retires final stores
    }
}

// ---------------- aggregation v5: fused fin epilogue, no global atomics -----
// wave per dst; 16 lanes x 8B cover one 128B h-row; quarter = lane>>4 picks
// the edge. edata[e] = (rel<<20)|src (4B); weight 1/cnt from wrow broadcast.
// Epilogue computes relu(acc_root + s + bias) and either (MODE 0) writes the
// H1 hi/lo split [replaces fin1] or (MODE 1) stores final values back to accb
// (plain coalesced stores; pooling done by pool_kernel -- the round-11 fused
// atomicAdd-to-pooled version serialized on 16KB of contended lines, 10x).
template <int MODE>
__global__ __launch_bounds__(256) void agg_kernel(const unsigned short* __restrict__ hc,
                                                  const int* __restrict__ rowptr,
                                                  const unsigned int* __restrict__ edata,
                                                  const float* __restrict__ wrow,
                                                  float* __restrict__ accb,
                                                  const float* __restrict__ bias,
                                                  unsigned short* __restrict__ hi,
                                                  unsigned short* __restrict__ lo,
                                                  int N) {
    int gid = blockIdx.x * 256 + threadIdx.x;
    int d = gid >> 6;
    if (d >= N) return;
    int lane = threadIdx.x & 63;
    int quarter = lane >> 4, l16 = lane & 15;
    float w10 = (lane < R_REL) ? wrow[d * R_REL + lane] : 0.f;
    int e0 = rowptr[d], e1 = rowptr[d + 1];
    int ne = e1 - e0;
    float s0 = 0.f, s1 = 0.f, s2 = 0.f, s3 = 0.f;
    for (int rb = 0; rb < ne; rb += 64) {
        int nthis = min(64, ne - rb);
        unsigned int k = (lane < nthis) ? edata[e0 + rb + lane] : 0u;
        int src = (int)(k & 0xFFFFFu);
        int rel = (int)(k >> 20);
        int off = (rel * N + src) << 6;          // * HD
        float wv = __shfl(w10, rel);
        if (lane >= nthis) wv = 0.f;             // pad lanes contribute 0
        for (int j = 0; j < nthis; j += 8) {
            int   oa = __shfl(off, j + quarter);
            float wa = __shfl(wv,  j + quarter);
            int   ob = __shfl(off, j + 4 + quarter);
            float wb = __shfl(wv,  j + 4 + quarter);
            uint2 da = *(const uint2*)(hc + oa + l16 * 4);
            uint2 db = *(const uint2*)(hc + ob + l16 * 4);
            s0 += wa * bf16lo(da.x); s1 += wa * bf16hi(da.x);
            s2 += wa * bf16lo(da.y); s3 += wa * bf16hi(da.y);
            s0 += wb * bf16lo(db.x); s1 += wb * bf16hi(db.x);
            s2 += wb * bf16lo(db.y); s3 += wb * bf16hi(db.y);
        }
    }
    s0 += __shfl_xor(s0, 16); s1 += __shfl_xor(s1, 16);
    s2 += __shfl_xor(s2, 16); s3 += __shfl_xor(s3, 16);
    s0 += __shfl_xor(s0, 32); s1 += __shfl_xor(s1, 32);
    s2 += __shfl_xor(s2, 32); s3 += __shfl_xor(s3, 32);
    if (lane < 16) {
        const float4 a = *(const float4*)(accb + (size_t)d * HD + l16 * 4);
        const float4 b4 = *(const float4*)(bias + l16 * 4);
        float v0 = fmaxf(a.x + s0 + b4.x, 0.f);
        float v1 = fmaxf(a.y + s1 + b4.y, 0.f);
        float v2 = fmaxf(a.z + s2 + b4.z, 0.f);
        float v3 = fmaxf(a.w + s3 + b4.w, 0.f);
        if (MODE == 0) {
            unsigned short h0 = f32_to_bf16_rne(v0), h1 = f32_to_bf16_rne(v1);
            unsigned short h2 = f32_to_bf16_rne(v2), h3 = f32_to_bf16_rne(v3);
            unsigned short l0 = f32_to_bf16_rne(v0 - bf16_to_f32(h0));
            unsigned short l1 = f32_to_bf16_rne(v1 - bf16_to_f32(h1));
            unsigned short l2 = f32_to_bf16_rne(v2 - bf16_to_f32(h2));
            unsigned short l3 = f32_to_bf16_rne(v3 - bf16_to_f32(h3));
            size_t o = (size_t)d * HD + l16 * 4;
            *(uint2*)(hi + o) = make_uint2((unsigned int)h0 | ((unsigned int)h1 << 16),
                                           (unsigned int)h2 | ((unsigned int)h3 << 16));
            *(uint2*)(lo + o) = make_uint2((unsigned int)l0 | ((unsigned int)l1 << 16),
                                           (unsigned int)l2 | ((unsigned int)l3 << 16));
        } else {
            float4 vout = make_float4(v0, v1, v2, v3);
            *(float4*)(accb + (size_t)d * HD + l16 * 4) = vout;
        }
    }
}

// ---------------- mean pool over final accb: wave per 64 sorted nodes -------
// batch is sorted; uniform fast path = 64 independent coalesced row loads and
// ONE atomic per lane per wave (contention-free, unlike fused atomics).
// Values in acc are already relu(.+bias) -- plain sum here.
__global__ __launch_bounds__(256) void pool_kernel(const float* __restrict__ acc,
                                                   const int* __restrict__ batch,
                                                   float* __restrict__ pooled,
                                                   float* __restrict__ gcnt, int N) {
    int w = blockIdx.x * 4 + (threadIdx.x >> 6);
    int lane = threadIdx.x & 63;
    int base = w * 64;
    if (base >= N) return;
    int nn = min(64, N - base);
    int g_l = (base + lane < N) ? batch[base + lane] : -1;
    int g_first = __shfl(g_l, 0);
    int g_last = __shfl(g_l, nn - 1);
    if (nn == 64 && g_first == g_last) {
        float p0 = 0.f, p1 = 0.f, p2 = 0.f, p3 = 0.f;
#pragma unroll
        for (int i = 0; i < 64; i += 4) {
            p0 += acc[(size_t)(base + i + 0) * HD + lane];
            p1 += acc[(size_t)(base + i + 1) * HD + lane];
            p2 += acc[(size_t)(base + i + 2) * HD + lane];
            p3 += acc[(size_t)(base + i + 3) * HD + lane];
        }
        atomicAdd(&pooled[g_first * HD + lane], (p0 + p1) + (p2 + p3));
        if (lane == 0) atomicAdd(&gcnt[g_first], 64.f);
    } else {
        int cur = g_first; float s = 0.f; int cnt = 0;
        for (int i = 0; i < nn; ++i) {
            int g = __shfl(g_l, i);
            if (g != cur) {
                atomicAdd(&pooled[cur * HD + lane], s);
                if (lane == 0) atomicAdd(&gcnt[cur], (float)cnt);
                cur = g; s = 0.f; cnt = 0;
            }
            s += acc[(size_t)(base + i) * HD + lane];
            cnt++;
        }
        atomicAdd(&pooled[cur * HD + lane], s);
        if (lane == 0) atomicAdd(&gcnt[cur], (float)cnt);
    }
}

__global__ void cls_kernel(const float* __restrict__ pooled, const float* __restrict__ gcnt,
                           const float* __restrict__ cls_w, const float* __restrict__ cls_b,
                           float* __restrict__ out) {
    int g = threadIdx.x;   // 64 graphs
    float invc = 1.0f / fmaxf(gcnt[g], 1.0f);
    float acc = 0.f;
    for (int j = 0; j < 64; ++j) acc += pooled[g * 64 + j] * cls_w[j];
    out[g] = acc * invc + cls_b[0];
}

extern "C" void kernel_launch(void* const* d_in, const int* in_sizes, int n_in,
                              void* d_out, int out_size, void* d_ws, size_t ws_size,
                              hipStream_t stream) {
    const float* x     = (const float*)d_in[0];
    const int*   eidx  = (const int*)d_in[1];
    const int*   et    = (const int*)d_in[2];
    const int*   batch = (const int*)d_in[3];
    const float* W1    = (const float*)d_in[4];
    const float* root1 = (const float*)d_in[5];
    const float* b1    = (const float*)d_in[6];
    const float* W2    = (const float*)d_in[7];
    const float* root2 = (const float*)d_in[8];
    const float* b2    = (const float*)d_in[9];
    const float* cls_w = (const float*)d_in[10];
    const float* cls_b = (const float*)d_in[11];

    const int N = in_sizes[3];
    const int E = in_sizes[2];
    const int NB = (N + 1023) / 1024;              // scan blocks over N
    const int NBK = (N + (1 << BSH) - 1) >> BSH;   // <=512 buckets
    const int* srcp = eidx;
    const int* dstp = eidx + E;

    char* ws = (char*)d_ws;
    size_t off = 0;
    auto alloc = [&](size_t bytes) -> void* {
        void* p = ws + off;
        off = (off + bytes + 255) & ~(size_t)255;
        return p;
    };
    unsigned short* Xhi  = (unsigned short*)alloc((size_t)N * 128 * 2);   // 25.6 MB
    unsigned short* Xlo  = (unsigned short*)alloc((size_t)N * 128 * 2);   // 25.6 MB
    float*          accb = (float*)alloc((size_t)N * HD * 4);             // 25.6 MB
    unsigned short* Wt1hi = (unsigned short*)alloc((size_t)(R_REL + 1) * HD * 128 * 2);
    unsigned short* Wt2hi = (unsigned short*)alloc((size_t)(R_REL + 1) * HD * HD * 2);
    unsigned int* edata  = (unsigned int*)alloc((size_t)E * 4);           // 12.8 MB
    float* wrow   = (float*)alloc((size_t)NBK * KPB * 4);                 // ~4 MB
    int*   rowptr = (int*)alloc((size_t)(N + 1) * 4);
    int*   dcnt   = (int*)alloc((size_t)N * 4);
    int*   bsum   = (int*)alloc((size_t)NB * 4);
    int*   bofs   = (int*)alloc((size_t)NB * 4);
    int*   bcnt   = (int*)alloc(512 * 4);
    int*   bboff  = (int*)alloc(513 * 4);
    int*   gcur   = (int*)alloc(512 * 4);
    float* pooled = (float*)alloc((size_t)(64 * HD + 64) * 4);
    float* gcnt   = pooled + 64 * HD;
    unsigned short* h_chunk = (unsigned short*)alloc((size_t)R_REL * N * HD * 2);  // 128 MB

    // aliases (stream-ordered, safe):
    // staged (12.8 MB packed) over Xhi: consumed by sortfill before split writes Xhi.
    // H1hi/H1lo over Xhi/Xlo: written by agg<0> AFTER the last gemm read of X.
    unsigned int* staged = (unsigned int*)Xhi;
    unsigned short* H1hi = Xhi;
    unsigned short* H1lo = Xlo;

    hipMemsetAsync(bcnt, 0, 512 * 4, stream);
    hipMemsetAsync(pooled, 0, (size_t)(64 * HD + 64) * 4, stream);

    // ---- bucketed CSR build: edata {(rel<<20)|src} + wrow + dst rowptr ----
    int nchunks = (E + 4095) / 4096;
    bhist_kernel<<<nchunks, 256, 0, stream>>>(dstp, bcnt, E);
    bscan_kernel<<<1, 512, 0, stream>>>(bcnt, bboff, gcur, NBK, E);
    bscatter_kernel<<<nchunks, 256, 0, stream>>>(srcp, dstp, et, gcur, staged, E);
    sortfill_kernel<<<NBK, 256, 0, stream>>>(staged, bboff, dcnt, edata, wrow, N, N);
    scan1_kernel<<<NB, 256, 0, stream>>>(dcnt, bsum, N);
    scan2_kernel<<<1, 1024, 0, stream>>>(bsum, bofs, NB);
    scan3_kernel<<<NB, 256, 0, stream>>>(dcnt, bofs, rowptr, N);

    // ---- precision-split operands (after staged is dead) ----
    int NK = N * 128;
    split_kernel<<<(NK + 255) / 256, 256, 0, stream>>>(x, Xhi, Xlo, NK);
    int tw1 = (R_REL + 1) * HD * 128, tw2 = (R_REL + 1) * HD * HD;
    wsplit_kernel<<<(tw1 + 255) / 256, 256, 0, stream>>>(W1, root1, Wt1hi, 128);
    wsplit_kernel<<<(tw2 + 255) / 256, 256, 0, stream>>>(W2, root2, Wt2hi, HD);

    const int gemmBlocks = (N + 127) / 128;
    const int aggBlocks  = (int)(((size_t)N * 64 + 255) / 256);

    // ---- layer 1 (K=128): rels 0..9 -> h_chunk, root -> accb; agg writes H1 ----
    gemm_mfma<128><<<gemmBlocks, 512, 0, stream>>>(Xhi, Xlo, Wt1hi, h_chunk, accb, N);
    agg_kernel<0><<<aggBlocks, 256, 0, stream>>>(h_chunk, rowptr, edata, wrow, accb, b1,
                                                 H1hi, H1lo, N);

    // ---- layer 2 (K=64): rels 0..9 -> h_chunk, root -> accb; agg finalizes accb ----
    gemm_mfma<64><<<gemmBlocks, 512, 0, stream>>>(H1hi, H1lo, Wt2hi, h_chunk, accb, N);
    agg_kernel<1><<<aggBlocks, 256, 0, stream>>>(h_chunk, rowptr, edata, wrow, accb, b2,
                                                 (unsigned short*)nullptr,
                                                 (unsigned short*)nullptr, N);

    // ---- pool (plain sum; values already relu(.+b2)) + classify ----
    int poolWaves = (N + 63) / 64;
    pool_kernel<<<(poolWaves + 3) / 4, 256, 0, stream>>>(accb, batch, pooled, gcnt, N);
    cls_kernel<<<1, 64, 0, stream>>>(pooled, gcnt, cls_w, cls_b, (float*)d_out);
}